// Round 1
// baseline (8233.167 us; speedup 1.0000x reference)
//
#include <hip/hip_runtime.h>
#include <hip/hip_cooperative_groups.h>
#include <math.h>

namespace cg = cooperative_groups;

#define BB 32     // batch
#define TT 128    // time steps
#define NF 256    // input features
#define HH 512    // hidden
#define G3 1536   // 3*H

// ---------------- K1: mx[t][b][j] = data[b][t][:] @ gru_kernel + b_in ----------------
// 512 blocks = 128 t * 4 bgroups(8 b each); 256 threads; thread handles 6 j * 8 b
__global__ __launch_bounds__(256) void k_mx(const float* __restrict__ data,
                                            const float* __restrict__ gk,
                                            const float* __restrict__ bias_in,
                                            float* __restrict__ mx) {
    __shared__ __align__(16) float xs[NF * 8];   // [k][bb]
    int bx = blockIdx.x;
    int t = bx >> 2, b0 = (bx & 3) * 8;
    int tid = threadIdx.x;
    for (int idx = tid; idx < 8 * NF; idx += 256) {
        int bb = idx >> 8, k = idx & 255;
        xs[k * 8 + bb] = data[((size_t)(b0 + bb) * TT + t) * NF + k];
    }
    __syncthreads();
    float acc[6][8];
#pragma unroll
    for (int jj = 0; jj < 6; jj++)
#pragma unroll
        for (int bb = 0; bb < 8; bb++) acc[jj][bb] = 0.f;

    for (int k = 0; k < NF; k++) {
        float4 xa = *(const float4*)&xs[k * 8];
        float4 xb = *(const float4*)&xs[k * 8 + 4];
        float xv[8] = {xa.x, xa.y, xa.z, xa.w, xb.x, xb.y, xb.z, xb.w};
#pragma unroll
        for (int jj = 0; jj < 6; jj++) {
            float g = gk[(size_t)k * G3 + jj * 256 + tid];
#pragma unroll
            for (int bb = 0; bb < 8; bb++) acc[jj][bb] += g * xv[bb];
        }
    }
#pragma unroll
    for (int jj = 0; jj < 6; jj++) {
        int j = jj * 256 + tid;
        float bi = bias_in[j];
#pragma unroll
        for (int bb = 0; bb < 8; bb++)
            mx[((size_t)t * BB + b0 + bb) * G3 + j] = acc[jj][bb] + bi;
    }
}

// ---------------- K2: sequential GRU, cooperative, 2 grid syncs/step ----------------
__device__ __forceinline__ float sigmoidf_(float x) { return 1.f / (1.f + __expf(-x)); }

// 256 WGs x 256 thr. wg -> ks(16) | bg(8, 4 b each) | ihalf(2)
__global__ __launch_bounds__(256, 2) void k_gru(const float* __restrict__ h0,
                                                const float* __restrict__ rk,
                                                const float* __restrict__ gbias,
                                                const float* __restrict__ mx,
                                                float* __restrict__ h,
                                                float* __restrict__ hs,
                                                float* __restrict__ P) {
    cg::grid_group grid = cg::this_grid();
    int tid = threadIdx.x;
    int wg = blockIdx.x;
    int ks = wg & 15;
    int bg = (wg >> 4) & 7;
    int ih = wg >> 7;
    int i = ih * 256 + tid;
    int b0 = bg * 4;
    int k0 = ks * 32;
    size_t gid = (size_t)wg * 256 + tid;

    __shared__ __align__(16) float hl[32 * 4];   // [kk][bb]

    if (gid < BB * HH) h[gid] = h0[gid];
    grid.sync();

    const float* brec = gbias + G3;

    for (int t = 0; t < TT; t++) {
        // ---- phase A: partial mh for (b0..b0+3, cols i, 512+i, 1024+i), k-chunk ks ----
        if (tid < 128) {
            int kk = tid >> 2, bb = tid & 3;
            hl[tid] = h[(size_t)(b0 + bb) * HH + k0 + kk];
        }
        __syncthreads();
        float az[4] = {0, 0, 0, 0}, ar[4] = {0, 0, 0, 0}, ah[4] = {0, 0, 0, 0};
#pragma unroll 8
        for (int kk = 0; kk < 32; kk++) {
            const float* rkk = rk + (size_t)(k0 + kk) * G3;
            float rz = rkk[i];
            float rr = rkk[512 + i];
            float rh = rkk[1024 + i];
            float4 hv = *(const float4*)&hl[kk * 4];
            float hv4[4] = {hv.x, hv.y, hv.z, hv.w};
#pragma unroll
            for (int bb = 0; bb < 4; bb++) {
                az[bb] += rz * hv4[bb];
                ar[bb] += rr * hv4[bb];
                ah[bb] += rh * hv4[bb];
            }
        }
#pragma unroll
        for (int bb = 0; bb < 4; bb++) {
            size_t base = ((size_t)ks * BB + b0 + bb) * G3;
            P[base + i] = az[bb];
            P[base + 512 + i] = ar[bb];
            P[base + 1024 + i] = ah[bb];
        }
        grid.sync();

        // ---- phase B: reduce partials, gates, h update ----
        if (gid < BB * HH) {
            int b = (int)(gid >> 9), ii = (int)(gid & 511);
            float zs = 0.f, rs = 0.f, hh = 0.f;
#pragma unroll
            for (int k2 = 0; k2 < 16; k2++) {
                size_t base = ((size_t)k2 * BB + b) * G3;
                zs += P[base + ii];
                rs += P[base + 512 + ii];
                hh += P[base + 1024 + ii];
            }
            const float* mxr = mx + ((size_t)t * BB + b) * G3;
            float z = sigmoidf_(mxr[ii] + zs + brec[ii]);
            float r = sigmoidf_(mxr[512 + ii] + rs + brec[512 + ii]);
            float c = tanhf(mxr[1024 + ii] + r * (hh + brec[1024 + ii]));
            float hold = h[gid];
            float hn = z * hold + (1.f - z) * c;
            h[gid] = hn;
            hs[((size_t)t * BB + b) * HH + ii] = hn;
        }
        grid.sync();
    }
}

// ---------------- K3: sx[b][u][n] = sum_t data[b][t][n] * w1[t][u] + w1b[u] ----------------
// 512 blocks = 32 b * 16 ugroups(8 u); 256 threads (one per n)
__global__ __launch_bounds__(256) void k_sx(const float* __restrict__ data,
                                            const float* __restrict__ w1,
                                            const float* __restrict__ w1b,
                                            float* __restrict__ sx) {
    int bx = blockIdx.x;
    int b = bx >> 4, ug = bx & 15;
    int n = threadIdx.x;
    float acc[8] = {0, 0, 0, 0, 0, 0, 0, 0};
    const float* dp = data + (size_t)b * TT * NF + n;
    for (int t = 0; t < TT; t++) {
        float x = dp[(size_t)t * NF];
#pragma unroll
        for (int uu = 0; uu < 8; uu++) acc[uu] += x * w1[t * TT + ug * 8 + uu];
    }
#pragma unroll
    for (int uu = 0; uu < 8; uu++) {
        int u = ug * 8 + uu;
        sx[((size_t)b * TT + u) * NF + n] = acc[uu] + w1b[u];
    }
}

// ---------------- K4: hp[r][u] = hs[r][:] @ w2 + w2b  (r = t*32+b) ----------------
// 512 blocks of 8 rows; 256 threads: u = tid&127, rh = tid>>7 (4 rows each)
__global__ __launch_bounds__(256) void k_hp(const float* __restrict__ hs,
                                            const float* __restrict__ w2,
                                            const float* __restrict__ w2b,
                                            float* __restrict__ hp) {
    __shared__ float hsl[8 * HH];   // 16KB
    int r0 = blockIdx.x * 8;
    int tid = threadIdx.x;
    for (int idx = tid; idx < 8 * HH; idx += 256)
        hsl[idx] = hs[(size_t)r0 * HH + idx];
    __syncthreads();
    int u = tid & 127, rh = tid >> 7;
    float acc[4] = {0, 0, 0, 0};
    for (int k = 0; k < HH; k++) {
        float w = w2[k * TT + u];
#pragma unroll
        for (int rr = 0; rr < 4; rr++) acc[rr] += hsl[(rh * 4 + rr) * HH + k] * w;
    }
    float wb = w2b[u];
#pragma unroll
    for (int rr = 0; rr < 4; rr++)
        hp[(size_t)(r0 + rh * 4 + rr) * TT + u] = acc[rr] + wb;
}

// ---------------- K5: fused score + softmax + output ----------------
// 4096 blocks (r = t*32+b); 256 threads (one per n)
__global__ __launch_bounds__(256) void k_attn(const float* __restrict__ data,
                                              const float* __restrict__ sx,
                                              const float* __restrict__ hp,
                                              const float* __restrict__ v_w,
                                              const float* __restrict__ v_b,
                                              float* __restrict__ out) {
    __shared__ float hv[TT];
    __shared__ float vv[TT];
    __shared__ float red[8];
    int r = blockIdx.x;
    int b = r & 31;
    int n = threadIdx.x;
    if (n < TT) {
        hv[n] = hp[(size_t)r * TT + n];
        vv[n] = v_w[n];
    }
    __syncthreads();
    float s = v_b[0];
    const float* sxp = sx + (size_t)b * TT * NF + n;
    for (int u = 0; u < TT; u++) {
        float e = tanhf(sxp[(size_t)u * NF] + hv[u]);
        s += vv[u] * e;
    }
    // softmax over 256 threads (features n)
    float m = s;
#pragma unroll
    for (int off = 32; off >= 1; off >>= 1) m = fmaxf(m, __shfl_xor(m, off));
    int lane = n & 63, wid = n >> 6;
    if (lane == 0) red[wid] = m;
    __syncthreads();
    float bm = fmaxf(fmaxf(red[0], red[1]), fmaxf(red[2], red[3]));
    float p = __expf(s - bm);
    float ps = p;
#pragma unroll
    for (int off = 32; off >= 1; off >>= 1) ps += __shfl_xor(ps, off);
    if (lane == 0) red[4 + wid] = ps;
    __syncthreads();
    float denom = red[4] + red[5] + red[6] + red[7];
    float alpha = p / denom;
    size_t idx = (size_t)r * NF + n;
    out[idx] = data[idx] * alpha;   // flat reshape equivalence: out.flat = data.flat * alpha.flat
}

extern "C" void kernel_launch(void* const* d_in, const int* in_sizes, int n_in,
                              void* d_out, int out_size, void* d_ws, size_t ws_size,
                              hipStream_t stream) {
    const float* data = (const float*)d_in[0];
    const float* h0   = (const float*)d_in[1];
    const float* gk   = (const float*)d_in[2];
    const float* rk   = (const float*)d_in[3];
    const float* gb   = (const float*)d_in[4];
    const float* w1   = (const float*)d_in[5];
    const float* w1b  = (const float*)d_in[6];
    const float* w2   = (const float*)d_in[7];
    const float* w2b  = (const float*)d_in[8];
    const float* vw   = (const float*)d_in[9];
    const float* vb   = (const float*)d_in[10];
    float* out = (float*)d_out;

    float* ws  = (float*)d_ws;
    float* mx  = ws;                    // 128*32*1536 = 6291456
    float* h   = mx + 6291456;          // 16384
    float* hs  = h + 16384;             // 2097152
    float* P   = hs + 2097152;          // 16*32*1536 = 786432
    float* sxb = P + 786432;            // 32*128*256 = 1048576
    float* hp  = sxb + 1048576;         // 128*32*128 = 524288

    k_mx<<<512, 256, 0, stream>>>(data, gk, gb, mx);

    void* args[] = {(void*)&h0, (void*)&rk, (void*)&gb, (void*)&mx,
                    (void*)&h, (void*)&hs, (void*)&P};
    hipLaunchCooperativeKernel((const void*)k_gru, dim3(256), dim3(256), args, 0, stream);

    k_sx<<<512, 256, 0, stream>>>(data, w1, w1b, sxb);
    k_hp<<<512, 256, 0, stream>>>(hs, w2, w2b, hp);
    k_attn<<<4096, 256, 0, stream>>>(data, sxb, hp, vw, vb, out);
}

// Round 2
// 3032.797 us; speedup vs baseline: 2.7147x; 2.7147x over previous
//
#include <hip/hip_runtime.h>
#include <math.h>

#define BB 32     // batch
#define TT 128    // time steps
#define NF 256    // input features
#define HH 512    // hidden
#define G3 1536   // 3*H

__device__ __forceinline__ float sigmoidf_(float x) { return 1.f / (1.f + __expf(-x)); }
__device__ __forceinline__ float tanh_fast(float x) {
    // 1 - 2/(e^{2x}+1); saturates correctly for |x| large (inf -> 1, 0 -> -1)
    float e = __expf(2.f * x);
    return 1.f - 2.f / (e + 1.f);
}

// ---------------- K0: transpose rk (512 x 1536) into k-blocked layout ----------------
// rkT[((k>>2)*1536 + col)*4 + (k&3)] = rk[k*1536 + col]
__global__ __launch_bounds__(256) void k_tr(const float* __restrict__ rk,
                                            float* __restrict__ rkT) {
    int k = blockIdx.x;
    const float* src = rk + (size_t)k * G3;
    size_t base = (size_t)(k >> 2) * G3 * 4 + (k & 3);
    for (int c = threadIdx.x; c < G3; c += 256)
        rkT[base + (size_t)c * 4] = src[c];
}

// ---------------- K1: mx[t][b][j] = data[b][t][:] @ gru_kernel + b_in ----------------
// 512 blocks = 128 t * 4 bgroups(8 b each); 256 threads; thread handles 6 j * 8 b
__global__ __launch_bounds__(256) void k_mx(const float* __restrict__ data,
                                            const float* __restrict__ gk,
                                            const float* __restrict__ bias_in,
                                            float* __restrict__ mx) {
    __shared__ __align__(16) float xs[NF * 8];   // [k][bb]
    int bx = blockIdx.x;
    int t = bx >> 2, b0 = (bx & 3) * 8;
    int tid = threadIdx.x;
    for (int idx = tid; idx < 8 * NF; idx += 256) {
        int bb = idx >> 8, k = idx & 255;
        xs[k * 8 + bb] = data[((size_t)(b0 + bb) * TT + t) * NF + k];
    }
    __syncthreads();
    float acc[6][8];
#pragma unroll
    for (int jj = 0; jj < 6; jj++)
#pragma unroll
        for (int bb = 0; bb < 8; bb++) acc[jj][bb] = 0.f;

    for (int k = 0; k < NF; k++) {
        float4 xa = *(const float4*)&xs[k * 8];
        float4 xb = *(const float4*)&xs[k * 8 + 4];
        float xv[8] = {xa.x, xa.y, xa.z, xa.w, xb.x, xb.y, xb.z, xb.w};
#pragma unroll
        for (int jj = 0; jj < 6; jj++) {
            float g = gk[(size_t)k * G3 + jj * 256 + tid];
#pragma unroll
            for (int bb = 0; bb < 8; bb++) acc[jj][bb] += g * xv[bb];
        }
    }
#pragma unroll
    for (int jj = 0; jj < 6; jj++) {
        int j = jj * 256 + tid;
        float bi = bias_in[j];
#pragma unroll
        for (int bb = 0; bb < 8; bb++)
            mx[((size_t)t * BB + b0 + bb) * G3 + j] = acc[jj][bb] + bi;
    }
}

// ---------------- K2: GRU — one workgroup per batch element, NO grid sync ----------------
// 32 WGs x 1024 threads. tid -> i = tid&511 (output column), half = tid>>9 (k-split).
// h lives in LDS for all 128 steps; rkT (3MB) stays hot in per-XCD L2.
__global__ __launch_bounds__(1024) void k_gru2(const float* __restrict__ h0,
                                               const float* __restrict__ rkT,
                                               const float* __restrict__ gbias,
                                               const float* __restrict__ mx,
                                               float* __restrict__ hs) {
    int b = blockIdx.x;
    int tid = threadIdx.x;
    int i = tid & 511;
    int half = tid >> 9;
    __shared__ __align__(16) float hcur[HH];
    __shared__ float paz[HH], par[HH], pah[HH];
    if (tid < HH) hcur[tid] = h0[b * HH + tid];
    const float* brec = gbias + G3;
    float bz = brec[i], brr = brec[512 + i], bh = brec[1024 + i];
    // rkT blocked layout: addr(kk, col, e) = kk*6144 + col*4 + e
    const float* pz = rkT + (size_t)half * 64 * 6144 + (size_t)i * 4;
    const float* pr = pz + 512 * 4;
    const float* pc = pz + 1024 * 4;
    const float4* hv = (const float4*)&hcur[half * 256];
    __syncthreads();

    for (int t = 0; t < TT; t++) {
        float az = 0.f, ar = 0.f, ah = 0.f;
#pragma unroll 4
        for (int kk = 0; kk < 64; kk++) {
            float4 h4 = hv[kk];                                   // LDS broadcast
            float4 z4 = *(const float4*)(pz + (size_t)kk * 6144); // coalesced 1KB/wave
            float4 r4 = *(const float4*)(pr + (size_t)kk * 6144);
            float4 c4 = *(const float4*)(pc + (size_t)kk * 6144);
            az += z4.x * h4.x + z4.y * h4.y + z4.z * h4.z + z4.w * h4.w;
            ar += r4.x * h4.x + r4.y * h4.y + r4.z * h4.z + r4.w * h4.w;
            ah += c4.x * h4.x + c4.y * h4.y + c4.z * h4.z + c4.w * h4.w;
        }
        if (half) { paz[i] = az; par[i] = ar; pah[i] = ah; }
        __syncthreads();
        if (!half) {
            az += paz[i]; ar += par[i]; ah += pah[i];
            const float* mxr = mx + ((size_t)t * BB + b) * G3;
            float z = sigmoidf_(mxr[i] + az + bz);
            float r = sigmoidf_(mxr[512 + i] + ar + brr);
            float c = tanhf(mxr[1024 + i] + r * (ah + bh));
            float hn = z * hcur[i] + (1.f - z) * c;
            hcur[i] = hn;
            hs[((size_t)t * BB + b) * HH + i] = hn;
        }
        __syncthreads();
    }
}

// ---------------- K3: sx[b][u][n] = sum_t data[b][t][n] * w1[t][u] + w1b[u] ----------------
__global__ __launch_bounds__(256) void k_sx(const float* __restrict__ data,
                                            const float* __restrict__ w1,
                                            const float* __restrict__ w1b,
                                            float* __restrict__ sx) {
    int bx = blockIdx.x;
    int b = bx >> 4, ug = bx & 15;
    int n = threadIdx.x;
    float acc[8] = {0, 0, 0, 0, 0, 0, 0, 0};
    const float* dp = data + (size_t)b * TT * NF + n;
    for (int t = 0; t < TT; t++) {
        float x = dp[(size_t)t * NF];
#pragma unroll
        for (int uu = 0; uu < 8; uu++) acc[uu] += x * w1[t * TT + ug * 8 + uu];
    }
#pragma unroll
    for (int uu = 0; uu < 8; uu++) {
        int u = ug * 8 + uu;
        sx[((size_t)b * TT + u) * NF + n] = acc[uu] + w1b[u];
    }
}

// ---------------- K4: hp[r][u] = hs[r][:] @ w2 + w2b  (r = t*32+b) ----------------
__global__ __launch_bounds__(256) void k_hp(const float* __restrict__ hs,
                                            const float* __restrict__ w2,
                                            const float* __restrict__ w2b,
                                            float* __restrict__ hp) {
    __shared__ float hsl[8 * HH];   // 16KB
    int r0 = blockIdx.x * 8;
    int tid = threadIdx.x;
    for (int idx = tid; idx < 8 * HH; idx += 256)
        hsl[idx] = hs[(size_t)r0 * HH + idx];
    __syncthreads();
    int u = tid & 127, rh = tid >> 7;
    float acc[4] = {0, 0, 0, 0};
    for (int k = 0; k < HH; k++) {
        float w = w2[k * TT + u];
#pragma unroll
        for (int rr = 0; rr < 4; rr++) acc[rr] += hsl[(rh * 4 + rr) * HH + k] * w;
    }
    float wb = w2b[u];
#pragma unroll
    for (int rr = 0; rr < 4; rr++)
        hp[(size_t)(r0 + rh * 4 + rr) * TT + u] = acc[rr] + wb;
}

// ---------------- K5: fused score + softmax + output ----------------
// 4096 blocks (r = t*32+b); 256 threads (one per n)
__global__ __launch_bounds__(256) void k_attn(const float* __restrict__ data,
                                              const float* __restrict__ sx,
                                              const float* __restrict__ hp,
                                              const float* __restrict__ v_w,
                                              const float* __restrict__ v_b,
                                              float* __restrict__ out) {
    __shared__ float hv[TT];
    __shared__ float vv[TT];
    __shared__ float red[8];
    int r = blockIdx.x;
    int b = r & 31;
    int n = threadIdx.x;
    if (n < TT) {
        hv[n] = hp[(size_t)r * TT + n];
        vv[n] = v_w[n];
    }
    __syncthreads();
    float s = v_b[0];
    const float* sxp = sx + (size_t)b * TT * NF + n;
    for (int u = 0; u < TT; u++) {
        float e = tanh_fast(sxp[(size_t)u * NF] + hv[u]);
        s += vv[u] * e;
    }
    // softmax over 256 threads (features n)
    float m = s;
#pragma unroll
    for (int off = 32; off >= 1; off >>= 1) m = fmaxf(m, __shfl_xor(m, off));
    int lane = n & 63, wid = n >> 6;
    if (lane == 0) red[wid] = m;
    __syncthreads();
    float bm = fmaxf(fmaxf(red[0], red[1]), fmaxf(red[2], red[3]));
    float p = __expf(s - bm);
    float ps = p;
#pragma unroll
    for (int off = 32; off >= 1; off >>= 1) ps += __shfl_xor(ps, off);
    if (lane == 0) red[4 + wid] = ps;
    __syncthreads();
    float denom = red[4] + red[5] + red[6] + red[7];
    float alpha = p / denom;
    size_t idx = (size_t)r * NF + n;
    out[idx] = data[idx] * alpha;   // flat reshape equivalence: out.flat = data.flat * alpha.flat
}

extern "C" void kernel_launch(void* const* d_in, const int* in_sizes, int n_in,
                              void* d_out, int out_size, void* d_ws, size_t ws_size,
                              hipStream_t stream) {
    const float* data = (const float*)d_in[0];
    const float* h0   = (const float*)d_in[1];
    const float* gk   = (const float*)d_in[2];
    const float* rk   = (const float*)d_in[3];
    const float* gb   = (const float*)d_in[4];
    const float* w1   = (const float*)d_in[5];
    const float* w1b  = (const float*)d_in[6];
    const float* w2   = (const float*)d_in[7];
    const float* w2b  = (const float*)d_in[8];
    const float* vw   = (const float*)d_in[9];
    const float* vb   = (const float*)d_in[10];
    float* out = (float*)d_out;

    float* ws  = (float*)d_ws;
    float* mx  = ws;                    // 128*32*1536 = 6291456
    float* hs  = mx + 6291456;          // 128*32*512  = 2097152
    float* rkT = hs + 2097152;          // 512*1536    = 786432
    float* sxb = rkT + 786432;          // 32*128*256  = 1048576
    float* hp  = sxb + 1048576;         // 128*32*128  = 524288

    k_tr<<<512, 256, 0, stream>>>(rk, rkT);
    k_mx<<<512, 256, 0, stream>>>(data, gk, gb, mx);
    k_gru2<<<BB, 1024, 0, stream>>>(h0, rkT, gb, mx, hs);
    k_sx<<<512, 256, 0, stream>>>(data, w1, w1b, sxb);
    k_hp<<<512, 256, 0, stream>>>(hs, w2, w2b, hp);
    k_attn<<<4096, 256, 0, stream>>>(data, sxb, hp, vw, vb, out);
}

// Round 3
// 2900.636 us; speedup vs baseline: 2.8384x; 1.0456x over previous
//
#include <hip/hip_runtime.h>
#include <math.h>

#define BB 32     // batch
#define TT 128    // time steps
#define NF 256    // input features
#define HH 512    // hidden
#define G3 1536   // 3*H
#define NWG 64    // GRU workgroups (column partition)

__device__ __forceinline__ float sigmoidf_(float x) { return 1.f / (1.f + __expf(-x)); }
__device__ __forceinline__ float tanh_fast(float x) {
    float e = __expf(2.f * x);
    return 1.f - 2.f / (e + 1.f);
}

// ---------------- K0: init h buffer (transpose h0 -> [i][b]) + zero barrier ----------------
__global__ __launch_bounds__(256) void k_hinit(const float* __restrict__ h0,
                                               float* __restrict__ hg2,
                                               unsigned int* __restrict__ bar) {
    int idx = blockIdx.x * 256 + threadIdx.x;   // 64 blocks -> 16384
    int i = idx & 511, b = idx >> 9;
    hg2[i * BB + b] = h0[b * HH + i];
    if (idx == 0) *bar = 0u;
}

// ---------------- K1: mx[t][b][j] = data[b][t][:] @ gru_kernel + b_in ----------------
__global__ __launch_bounds__(256) void k_mx(const float* __restrict__ data,
                                            const float* __restrict__ gk,
                                            const float* __restrict__ bias_in,
                                            float* __restrict__ mx) {
    __shared__ __align__(16) float xs[NF * 8];   // [k][bb]
    int bx = blockIdx.x;
    int t = bx >> 2, b0 = (bx & 3) * 8;
    int tid = threadIdx.x;
    for (int idx = tid; idx < 8 * NF; idx += 256) {
        int bb = idx >> 8, k = idx & 255;
        xs[k * 8 + bb] = data[((size_t)(b0 + bb) * TT + t) * NF + k];
    }
    __syncthreads();
    float acc[6][8];
#pragma unroll
    for (int jj = 0; jj < 6; jj++)
#pragma unroll
        for (int bb = 0; bb < 8; bb++) acc[jj][bb] = 0.f;

    for (int k = 0; k < NF; k++) {
        float4 xa = *(const float4*)&xs[k * 8];
        float4 xb = *(const float4*)&xs[k * 8 + 4];
        float xv[8] = {xa.x, xa.y, xa.z, xa.w, xb.x, xb.y, xb.z, xb.w};
#pragma unroll
        for (int jj = 0; jj < 6; jj++) {
            float g = gk[(size_t)k * G3 + jj * 256 + tid];
#pragma unroll
            for (int bb = 0; bb < 8; bb++) acc[jj][bb] += g * xv[bb];
        }
    }
#pragma unroll
    for (int jj = 0; jj < 6; jj++) {
        int j = jj * 256 + tid;
        float bi = bias_in[j];
#pragma unroll
        for (int bb = 0; bb < 8; bb++)
            mx[((size_t)t * BB + b0 + bb) * G3 + j] = acc[jj][bb] + bi;
    }
}

// ---------------- K2: GRU — column-partitioned, weights resident in LDS ----------------
// 64 WGs x 256 threads, cooperative. WG owns h-cols i0..i0+7 for ALL 32 batches.
// thread: jj = tid>>5 (col within slice), b = tid&31 (batch).
// Per step: stage full h (64KB) into LDS, matvec from LDS-resident weights,
// write h slice to global double buffer, agent-scope counter barrier.
extern __shared__ float4 wl4_dyn[];   // 512*8 float4 = 64 KB: {wz,wr,wc,pad} per (k,jj)

__global__ __launch_bounds__(256, 1) void k_gru3(const float* __restrict__ rk,
                                                 const float* __restrict__ gbias,
                                                 const float* __restrict__ mx,
                                                 float* __restrict__ hg2,
                                                 float* __restrict__ hs,
                                                 unsigned int* __restrict__ bar) {
    __shared__ __align__(16) float h_all[HH * BB];   // 64 KB, layout [k][b]
    int wg = blockIdx.x;
    int tid = threadIdx.x;
    int jj = tid >> 5;
    int b = tid & 31;
    int i0 = wg * 8;
    int i = i0 + jj;

    // one-time: stage weight slice into LDS (read once from HBM/L2 total across WGs)
    for (int idx = tid; idx < HH * 8; idx += 256) {
        int k = idx >> 3, j2 = idx & 7;
        const float* r = rk + (size_t)k * G3 + i0 + j2;
        wl4_dyn[idx] = make_float4(r[0], r[512], r[1024], 0.f);
    }
    const float* brec = gbias + G3;
    float bz = brec[i], brr = brec[512 + i], bh = brec[1024 + i];

    unsigned int target = 0;
    for (int t = 0; t < TT; t++) {
        // mx loads are barrier-independent: issue early, waitcnt lands after inner loop
        const float* mxr = mx + ((size_t)t * BB + b) * G3 + i0 + jj;
        float mz = mxr[0], mr = mxr[512], mh = mxr[1024];

        if (t > 0) {
            if (tid == 0) {
                while (__hip_atomic_load(bar, __ATOMIC_ACQUIRE, __HIP_MEMORY_SCOPE_AGENT) < target)
                    __builtin_amdgcn_s_sleep(1);
            }
        }
        __syncthreads();   // t=0: also covers weight staging

        // stage h[t&1] -> LDS (coalesced float4, conflict-free writes)
        const float4* hgr = (const float4*)(hg2 + (t & 1) * (HH * BB));
        float4* hl4 = (float4*)h_all;
#pragma unroll
        for (int it = 0; it < 16; it++) {
            int idx = it * 256 + tid;
            hl4[idx] = hgr[idx];
        }
        __syncthreads();

        float az = 0.f, ar = 0.f, ah = 0.f;
        const float4* wp = wl4_dyn + jj;
        const float* hp_ = h_all + b;
#pragma unroll 8
        for (int k = 0; k < HH; k++) {
            float4 w4 = wp[(size_t)k * 8];     // ds_read_b128, 2 distinct addrs/wave (broadcast)
            float hk = hp_[(size_t)k * 32];    // ds_read_b32, 32 distinct banks, conflict-free
            az += w4.x * hk;
            ar += w4.y * hk;
            ah += w4.z * hk;
        }
        float z = sigmoidf_(mz + az + bz);
        float r = sigmoidf_(mr + ar + brr);
        float c = tanhf(mh + r * (ah + bh));
        float hold = h_all[(size_t)i * 32 + b];
        float hn = z * hold + (1.f - z) * c;

        hg2[((t + 1) & 1) * (HH * BB) + i * 32 + b] = hn;   // coalesced across lanes
        hs[((size_t)t * BB + b) * HH + i] = hn;
        target += NWG;

        __threadfence();       // agent-scope release of this thread's h writes
        __syncthreads();       // all threads' fences done before arrival
        if (tid == 0)
            __hip_atomic_fetch_add(bar, 1u, __ATOMIC_RELEASE, __HIP_MEMORY_SCOPE_AGENT);
    }
}

// ---------------- K3: sx[b][u][n] = sum_t data[b][t][n] * w1[t][u] + w1b[u] ----------------
__global__ __launch_bounds__(256) void k_sx(const float* __restrict__ data,
                                            const float* __restrict__ w1,
                                            const float* __restrict__ w1b,
                                            float* __restrict__ sx) {
    int bx = blockIdx.x;
    int b = bx >> 4, ug = bx & 15;
    int n = threadIdx.x;
    float acc[8] = {0, 0, 0, 0, 0, 0, 0, 0};
    const float* dp = data + (size_t)b * TT * NF + n;
    for (int t = 0; t < TT; t++) {
        float x = dp[(size_t)t * NF];
#pragma unroll
        for (int uu = 0; uu < 8; uu++) acc[uu] += x * w1[t * TT + ug * 8 + uu];
    }
#pragma unroll
    for (int uu = 0; uu < 8; uu++) {
        int u = ug * 8 + uu;
        sx[((size_t)b * TT + u) * NF + n] = acc[uu] + w1b[u];
    }
}

// ---------------- K4: hp[r][u] = hs[r][:] @ w2 + w2b  (r = t*32+b) ----------------
__global__ __launch_bounds__(256) void k_hp(const float* __restrict__ hs,
                                            const float* __restrict__ w2,
                                            const float* __restrict__ w2b,
                                            float* __restrict__ hp) {
    __shared__ float hsl[8 * HH];   // 16KB
    int r0 = blockIdx.x * 8;
    int tid = threadIdx.x;
    for (int idx = tid; idx < 8 * HH; idx += 256)
        hsl[idx] = hs[(size_t)r0 * HH + idx];
    __syncthreads();
    int u = tid & 127, rh = tid >> 7;
    float acc[4] = {0, 0, 0, 0};
    for (int k = 0; k < HH; k++) {
        float w = w2[k * TT + u];
#pragma unroll
        for (int rr = 0; rr < 4; rr++) acc[rr] += hsl[(rh * 4 + rr) * HH + k] * w;
    }
    float wb = w2b[u];
#pragma unroll
    for (int rr = 0; rr < 4; rr++)
        hp[(size_t)(r0 + rh * 4 + rr) * TT + u] = acc[rr] + wb;
}

// ---------------- K5: fused score + softmax + output ----------------
__global__ __launch_bounds__(256) void k_attn(const float* __restrict__ data,
                                              const float* __restrict__ sx,
                                              const float* __restrict__ hp,
                                              const float* __restrict__ v_w,
                                              const float* __restrict__ v_b,
                                              float* __restrict__ out) {
    __shared__ float hv[TT];
    __shared__ float vv[TT];
    __shared__ float red[8];
    int r = blockIdx.x;
    int b = r & 31;
    int n = threadIdx.x;
    if (n < TT) {
        hv[n] = hp[(size_t)r * TT + n];
        vv[n] = v_w[n];
    }
    __syncthreads();
    float s = v_b[0];
    const float* sxp = sx + (size_t)b * TT * NF + n;
    for (int u = 0; u < TT; u++) {
        float e = tanh_fast(sxp[(size_t)u * NF] + hv[u]);
        s += vv[u] * e;
    }
    float m = s;
#pragma unroll
    for (int off = 32; off >= 1; off >>= 1) m = fmaxf(m, __shfl_xor(m, off));
    int lane = n & 63, wid = n >> 6;
    if (lane == 0) red[wid] = m;
    __syncthreads();
    float bm = fmaxf(fmaxf(red[0], red[1]), fmaxf(red[2], red[3]));
    float p = __expf(s - bm);
    float ps = p;
#pragma unroll
    for (int off = 32; off >= 1; off >>= 1) ps += __shfl_xor(ps, off);
    if (lane == 0) red[4 + wid] = ps;
    __syncthreads();
    float denom = red[4] + red[5] + red[6] + red[7];
    float alpha = p / denom;
    size_t idx = (size_t)r * NF + n;
    out[idx] = data[idx] * alpha;
}

extern "C" void kernel_launch(void* const* d_in, const int* in_sizes, int n_in,
                              void* d_out, int out_size, void* d_ws, size_t ws_size,
                              hipStream_t stream) {
    const float* data = (const float*)d_in[0];
    const float* h0   = (const float*)d_in[1];
    const float* gk   = (const float*)d_in[2];
    const float* rk   = (const float*)d_in[3];
    const float* gb   = (const float*)d_in[4];
    const float* w1   = (const float*)d_in[5];
    const float* w1b  = (const float*)d_in[6];
    const float* w2   = (const float*)d_in[7];
    const float* w2b  = (const float*)d_in[8];
    const float* vw   = (const float*)d_in[9];
    const float* vb   = (const float*)d_in[10];
    float* out = (float*)d_out;

    float* ws  = (float*)d_ws;
    float* mx  = ws;                    // 128*32*1536 = 6291456
    float* hs  = mx + 6291456;          // 128*32*512  = 2097152
    float* sxb = hs + 2097152;          // 32*128*256  = 1048576
    float* hp  = sxb + 1048576;         // 128*32*128  = 524288
    float* hg2 = hp + 524288;           // 2*512*32    = 32768
    unsigned int* bar = (unsigned int*)(hg2 + 32768);

    k_hinit<<<64, 256, 0, stream>>>(h0, hg2, bar);
    k_mx<<<512, 256, 0, stream>>>(data, gk, gb, mx);

    void* args[] = {(void*)&rk, (void*)&gb, (void*)&mx,
                    (void*)&hg2, (void*)&hs, (void*)&bar};
    hipLaunchCooperativeKernel((const void*)k_gru3, dim3(NWG), dim3(256), args,
                               65536, stream);

    k_sx<<<512, 256, 0, stream>>>(data, w1, w1b, sxb);
    k_hp<<<512, 256, 0, stream>>>(hs, w2, w2b, hp);
    k_attn<<<4096, 256, 0, stream>>>(data, sxb, hp, vw, vb, out);
}

// Round 8
// 2776.815 us; speedup vs baseline: 2.9650x; 1.0446x over previous
//
#include <hip/hip_runtime.h>
#include <math.h>

#define BB 32     // batch
#define TT 128    // time steps
#define NF 256    // input features
#define HH 512    // hidden
#define G3 1536   // 3*H
#define NWG 64    // GRU workgroups (column partition)
#define NGRP 8    // barrier groups (8 WGs each)

__device__ __forceinline__ float sigmoidf_(float x) { return 1.f / (1.f + __expf(-x)); }
__device__ __forceinline__ float tanh_fast(float x) {
    float e = __expf(2.f * x);
    return 1.f - 2.f / (e + 1.f);
}

// ---------------- K0: init h buffer (transpose h0 -> [i][b]) + zero group counters ----------------
__global__ __launch_bounds__(256) void k_hinit(const float* __restrict__ h0,
                                               float* __restrict__ hg2,
                                               unsigned int* __restrict__ grp) {
    int idx = blockIdx.x * 256 + threadIdx.x;   // 64 blocks -> 16384
    int i = idx & 511, b = idx >> 9;
    hg2[i * BB + b] = h0[b * HH + i];
    if (idx < 128) grp[idx] = 0u;               // 8 group lines x 16 dwords (64B spacing)
}

// ---------------- K1: mx[t][b][j] = data[b][t][:] @ gru_kernel + b_in ----------------
__global__ __launch_bounds__(256) void k_mx(const float* __restrict__ data,
                                            const float* __restrict__ gk,
                                            const float* __restrict__ bias_in,
                                            float* __restrict__ mx) {
    __shared__ __align__(16) float xs[NF * 8];   // [k][bb]
    int bx = blockIdx.x;
    int t = bx >> 2, b0 = (bx & 3) * 8;
    int tid = threadIdx.x;
    for (int idx = tid; idx < 8 * NF; idx += 256) {
        int bb = idx >> 8, k = idx & 255;
        xs[k * 8 + bb] = data[((size_t)(b0 + bb) * TT + t) * NF + k];
    }
    __syncthreads();
    float acc[6][8];
#pragma unroll
    for (int jj = 0; jj < 6; jj++)
#pragma unroll
        for (int bb = 0; bb < 8; bb++) acc[jj][bb] = 0.f;

    for (int k = 0; k < NF; k++) {
        float4 xa = *(const float4*)&xs[k * 8];
        float4 xb = *(const float4*)&xs[k * 8 + 4];
        float xv[8] = {xa.x, xa.y, xa.z, xa.w, xb.x, xb.y, xb.z, xb.w};
#pragma unroll
        for (int jj = 0; jj < 6; jj++) {
            float g = gk[(size_t)k * G3 + jj * 256 + tid];
#pragma unroll
            for (int bb = 0; bb < 8; bb++) acc[jj][bb] += g * xv[bb];
        }
    }
#pragma unroll
    for (int jj = 0; jj < 6; jj++) {
        int j = jj * 256 + tid;
        float bi = bias_in[j];
#pragma unroll
        for (int bb = 0; bb < 8; bb++)
            mx[((size_t)t * BB + b0 + bb) * G3 + j] = acc[jj][bb] + bi;
    }
}

// ---------------- K2: GRU — ROUND-3 KERNEL VERBATIM except 2-level barrier ----------------
// 64 WGs x 256 threads, cooperative. WG owns h-cols i0..i0+7 for ALL 32 batches.
// thread: jj = tid>>5 (col within slice), b = tid&31 (batch).
// Per step: stage full h (64KB) into LDS, matvec from LDS-resident weights,
// write h slice to global double buffer, two-level agent-scope counter barrier:
// arrival = RMW on group line (wg>>3), wait = 8 threads poll the 8 group lines.
extern __shared__ float4 wl4_dyn[];   // 512*8 float4 = 64 KB: {wz,wr,wc,pad} per (k,jj)

__global__ __launch_bounds__(256, 1) void k_gru8(const float* __restrict__ rk,
                                                 const float* __restrict__ gbias,
                                                 const float* __restrict__ mx,
                                                 float* __restrict__ hg2,
                                                 float* __restrict__ hs,
                                                 unsigned int* __restrict__ grp) {
    __shared__ __align__(16) float h_all[HH * BB];   // 64 KB, layout [k][b]
    int wg = blockIdx.x;
    int tid = threadIdx.x;
    int jj = tid >> 5;
    int b = tid & 31;
    int i0 = wg * 8;
    int i = i0 + jj;

    // one-time: stage weight slice into LDS (read once from HBM/L2 total across WGs)
    for (int idx = tid; idx < HH * 8; idx += 256) {
        int k = idx >> 3, j2 = idx & 7;
        const float* r = rk + (size_t)k * G3 + i0 + j2;
        wl4_dyn[idx] = make_float4(r[0], r[512], r[1024], 0.f);
    }
    const float* brec = gbias + G3;
    float bz = brec[i], brr = brec[512 + i], bh = brec[1024 + i];

    for (int t = 0; t < TT; t++) {
        // ---- two-level wait: 8 threads each poll one group line ----
        if (t > 0) {
            if (tid < NGRP) {
                const unsigned int tgt = (unsigned int)t * (NWG / NGRP);
                while (__hip_atomic_load(&grp[tid * 16], __ATOMIC_ACQUIRE,
                                         __HIP_MEMORY_SCOPE_AGENT) < tgt)
                    __builtin_amdgcn_s_sleep(1);
            }
        }
        __syncthreads();   // t=0: also covers weight staging

        // ---- stage h[t&1] -> LDS (coalesced float4, conflict-free writes) ----
        const float4* hgr = (const float4*)(hg2 + (t & 1) * (HH * BB));
        float4* hl4 = (float4*)h_all;
#pragma unroll
        for (int it = 0; it < 16; it++) {
            int idx = it * 256 + tid;
            hl4[idx] = hgr[idx];
        }
        __syncthreads();

        // mx loads (issued here as in round 3; waitcnt lands after inner loop)
        const float* mxr = mx + ((size_t)t * BB + b) * G3 + i0 + jj;
        float mz = mxr[0], mr = mxr[512], mh = mxr[1024];

        float az = 0.f, ar = 0.f, ah = 0.f;
        const float4* wp = wl4_dyn + jj;
        const float* hp_ = h_all + b;
#pragma unroll 8
        for (int k = 0; k < HH; k++) {
            float4 w4 = wp[(size_t)k * 8];     // ds_read_b128, 2 distinct addrs/wave (broadcast)
            float hk = hp_[(size_t)k * 32];    // ds_read_b32, 32 distinct banks, conflict-free
            az += w4.x * hk;
            ar += w4.y * hk;
            ah += w4.z * hk;
        }
        float z = sigmoidf_(mz + az + bz);
        float r = sigmoidf_(mr + ar + brr);
        float c = tanhf(mh + r * (ah + bh));
        float hold = h_all[(size_t)i * 32 + b];
        float hn = z * hold + (1.f - z) * c;

        hg2[((t + 1) & 1) * (HH * BB) + i * 32 + b] = hn;   // coalesced across lanes
        hs[((size_t)t * BB + b) * HH + i] = hn;

        __threadfence();       // agent-scope release of this thread's h writes
        __syncthreads();       // all threads' fences done before arrival
        if (tid == 0)
            __hip_atomic_fetch_add(&grp[(wg >> 3) * 16], 1u,
                                   __ATOMIC_RELEASE, __HIP_MEMORY_SCOPE_AGENT);
    }
}

// ---------------- K3: sx[b][u][n] = sum_t data[b][t][n] * w1[t][u] + w1b[u] ----------------
__global__ __launch_bounds__(256) void k_sx(const float* __restrict__ data,
                                            const float* __restrict__ w1,
                                            const float* __restrict__ w1b,
                                            float* __restrict__ sx) {
    int bx = blockIdx.x;
    int b = bx >> 4, ug = bx & 15;
    int n = threadIdx.x;
    float acc[8] = {0, 0, 0, 0, 0, 0, 0, 0};
    const float* dp = data + (size_t)b * TT * NF + n;
    for (int t = 0; t < TT; t++) {
        float x = dp[(size_t)t * NF];
#pragma unroll
        for (int uu = 0; uu < 8; uu++) acc[uu] += x * w1[t * TT + ug * 8 + uu];
    }
#pragma unroll
    for (int uu = 0; uu < 8; uu++) {
        int u = ug * 8 + uu;
        sx[((size_t)b * TT + u) * NF + n] = acc[uu] + w1b[u];
    }
}

// ---------------- K4: hp[r][u] = hs[r][:] @ w2 + w2b  (r = t*32+b) ----------------
__global__ __launch_bounds__(256) void k_hp(const float* __restrict__ hs,
                                            const float* __restrict__ w2,
                                            const float* __restrict__ w2b,
                                            float* __restrict__ hp) {
    __shared__ float hsl[8 * HH];   // 16KB
    int r0 = blockIdx.x * 8;
    int tid = threadIdx.x;
    for (int idx = tid; idx < 8 * HH; idx += 256)
        hsl[idx] = hs[(size_t)r0 * HH + idx];
    __syncthreads();
    int u = tid & 127, rh = tid >> 7;
    float acc[4] = {0, 0, 0, 0};
    for (int k = 0; k < HH; k++) {
        float w = w2[k * TT + u];
#pragma unroll
        for (int rr = 0; rr < 4; rr++) acc[rr] += hsl[(rh * 4 + rr) * HH + k] * w;
    }
    float wb = w2b[u];
#pragma unroll
    for (int rr = 0; rr < 4; rr++)
        hp[(size_t)(r0 + rh * 4 + rr) * TT + u] = acc[rr] + wb;
}

// ---------------- K5: fused score + softmax + output ----------------
__global__ __launch_bounds__(256) void k_attn(const float* __restrict__ data,
                                              const float* __restrict__ sx,
                                              const float* __restrict__ hp,
                                              const float* __restrict__ v_w,
                                              const float* __restrict__ v_b,
                                              float* __restrict__ out) {
    __shared__ float hv[TT];
    __shared__ float vv[TT];
    __shared__ float red[8];
    int r = blockIdx.x;
    int b = r & 31;
    int n = threadIdx.x;
    if (n < TT) {
        hv[n] = hp[(size_t)r * TT + n];
        vv[n] = v_w[n];
    }
    __syncthreads();
    float s = v_b[0];
    const float* sxp = sx + (size_t)b * TT * NF + n;
    for (int u = 0; u < TT; u++) {
        float e = tanh_fast(sxp[(size_t)u * NF] + hv[u]);
        s += vv[u] * e;
    }
    float m = s;
#pragma unroll
    for (int off = 32; off >= 1; off >>= 1) m = fmaxf(m, __shfl_xor(m, off));
    int lane = n & 63, wid = n >> 6;
    if (lane == 0) red[wid] = m;
    __syncthreads();
    float bm = fmaxf(fmaxf(red[0], red[1]), fmaxf(red[2], red[3]));
    float p = __expf(s - bm);
    float ps = p;
#pragma unroll
    for (int off = 32; off >= 1; off >>= 1) ps += __shfl_xor(ps, off);
    if (lane == 0) red[4 + wid] = ps;
    __syncthreads();
    float denom = red[4] + red[5] + red[6] + red[7];
    float alpha = p / denom;
    size_t idx = (size_t)r * NF + n;
    out[idx] = data[idx] * alpha;
}

extern "C" void kernel_launch(void* const* d_in, const int* in_sizes, int n_in,
                              void* d_out, int out_size, void* d_ws, size_t ws_size,
                              hipStream_t stream) {
    const float* data = (const float*)d_in[0];
    const float* h0   = (const float*)d_in[1];
    const float* gk   = (const float*)d_in[2];
    const float* rk   = (const float*)d_in[3];
    const float* gb   = (const float*)d_in[4];
    const float* w1   = (const float*)d_in[5];
    const float* w1b  = (const float*)d_in[6];
    const float* w2   = (const float*)d_in[7];
    const float* w2b  = (const float*)d_in[8];
    const float* vw   = (const float*)d_in[9];
    const float* vb   = (const float*)d_in[10];
    float* out = (float*)d_out;

    float* ws  = (float*)d_ws;
    float* mx  = ws;                    // 128*32*1536 = 6291456
    float* hs  = mx + 6291456;          // 128*32*512  = 2097152
    float* sxb = hs + 2097152;          // 32*128*256  = 1048576
    float* hp  = sxb + 1048576;         // 128*32*128  = 524288
    float* hg2 = hp + 524288;           // 2*512*32    = 32768
    unsigned int* grp = (unsigned int*)(hg2 + 32768);   // 8 lines x 16 dwords

    k_hinit<<<64, 256, 0, stream>>>(h0, hg2, grp);
    k_mx<<<512, 256, 0, stream>>>(data, gk, gb, mx);

    void* args[] = {(void*)&rk, (void*)&gb, (void*)&mx,
                    (void*)&hg2, (void*)&hs, (void*)&grp};
    hipLaunchCooperativeKernel((const void*)k_gru8, dim3(NWG), dim3(256), args,
                               65536, stream);

    k_sx<<<512, 256, 0, stream>>>(data, w1, w1b, sxb);
    k_hp<<<512, 256, 0, stream>>>(hs, w2, w2b, hp);
    k_attn<<<4096, 256, 0, stream>>>(data, sxb, hp, vw, vb, out);
}

// Round 9
// 2212.070 us; speedup vs baseline: 3.7219x; 1.2553x over previous
//
#include <hip/hip_runtime.h>
#include <math.h>

#define BB 32     // batch
#define TT 128    // time steps
#define NF 256    // input features
#define HH 512    // hidden
#define G3 1536   // 3*H
#define NWG 64    // GRU workgroups (column partition)
#define NGRP 8    // barrier groups (8 WGs each)

__device__ __forceinline__ float sigmoidf_(float x) { return 1.f / (1.f + __expf(-x)); }
__device__ __forceinline__ float tanh_fast(float x) {
    float e = __expf(2.f * x);
    return 1.f - 2.f / (e + 1.f);
}
__device__ __forceinline__ float sel4_(float a0, float a1, float a2, float a3, int s) {
    float s01 = (s & 1) ? a1 : a0;
    float s23 = (s & 1) ? a3 : a2;
    return (s & 2) ? s23 : s01;
}

// ---------------- K0: init h buffer (transpose h0 -> [i][b]) + zero group counters ----------------
__global__ __launch_bounds__(256) void k_hinit(const float* __restrict__ h0,
                                               float* __restrict__ hg2,
                                               unsigned int* __restrict__ grp) {
    int idx = blockIdx.x * 256 + threadIdx.x;   // 64 blocks -> 16384
    int i = idx & 511, b = idx >> 9;
    hg2[i * BB + b] = h0[b * HH + i];
    if (idx < 128) grp[idx] = 0u;               // 8 group lines x 16 dwords (64B spacing)
}

// ---------------- K1: mx[t][b][j] = data[b][t][:] @ gru_kernel + b_in ----------------
__global__ __launch_bounds__(256) void k_mx(const float* __restrict__ data,
                                            const float* __restrict__ gk,
                                            const float* __restrict__ bias_in,
                                            float* __restrict__ mx) {
    __shared__ __align__(16) float xs[NF * 8];   // [k][bb]
    int bx = blockIdx.x;
    int t = bx >> 2, b0 = (bx & 3) * 8;
    int tid = threadIdx.x;
    for (int idx = tid; idx < 8 * NF; idx += 256) {
        int bb = idx >> 8, k = idx & 255;
        xs[k * 8 + bb] = data[((size_t)(b0 + bb) * TT + t) * NF + k];
    }
    __syncthreads();
    float acc[6][8];
#pragma unroll
    for (int jj = 0; jj < 6; jj++)
#pragma unroll
        for (int bb = 0; bb < 8; bb++) acc[jj][bb] = 0.f;

    for (int k = 0; k < NF; k++) {
        float4 xa = *(const float4*)&xs[k * 8];
        float4 xb = *(const float4*)&xs[k * 8 + 4];
        float xv[8] = {xa.x, xa.y, xa.z, xa.w, xb.x, xb.y, xb.z, xb.w};
#pragma unroll
        for (int jj = 0; jj < 6; jj++) {
            float g = gk[(size_t)k * G3 + jj * 256 + tid];
#pragma unroll
            for (int bb = 0; bb < 8; bb++) acc[jj][bb] += g * xv[bb];
        }
    }
#pragma unroll
    for (int jj = 0; jj < 6; jj++) {
        int j = jj * 256 + tid;
        float bi = bias_in[j];
#pragma unroll
        for (int bb = 0; bb < 8; bb++)
            mx[((size_t)t * BB + b0 + bb) * G3 + j] = acc[jj][bb] + bi;
    }
}

// ---------------- K2: GRU — quad-read inner loop (12 FMA / 2 LDS), r8-proven envelope ----------------
// 64 WGs x 256 threads, cooperative, 1 WG/CU. Thread = (jj = tid>>5: col, bq = (tid>>2)&7:
// batch quad, ks = tid&3: k-split of 128 k each). Per k: one b128 weight read (8-way lane
// broadcast) + one b128 h-quad read -> 12 FMA. In-wave shfl_xor butterfly over ks lanes
// reduces k-partials; lane takes c=ks so each thread finishes (col i, batch bq*4+ks).
// LDS: 64KB static h (float4/quad, XOR bank swizzle per 128-k block) + 64KB dynamic
// weights (same swizzle). Barrier: r8-proven two-level group counters.
extern __shared__ float4 wl4_dyn[];   // 512*8 float4 = 64 KB: {wz,wr,wc,pad} per (k,col), swizzled

__global__ __launch_bounds__(256, 1) void k_gru9(const float* __restrict__ rk,
                                                 const float* __restrict__ gbias,
                                                 const float* __restrict__ mx,
                                                 float* __restrict__ hg2,
                                                 float* __restrict__ hs,
                                                 unsigned int* __restrict__ grp) {
    __shared__ __align__(16) float4 h4[HH * 8];   // 64 KB: h[k][batch-quad], swizzled
    const int tid = threadIdx.x;
    const int wg  = blockIdx.x;
    const int jj  = tid >> 5;          // 0..7 column within slice
    const int bq  = (tid >> 2) & 7;    // 0..7 batch quad
    const int ks  = tid & 3;           // 0..3 k-split (128 k each)
    const int i0  = wg * 8;
    const int i   = i0 + jj;
    const int batch = bq * 4 + ks;
    const int jjs = jj ^ (ks << 1);    // swizzled weight slot for this thread's k-range
    const int bqs = bq ^ (ks << 1);    // swizzled h slot for this thread's k-range

    // one-time: weight slice -> dynamic LDS, bank-swizzled.
    // physical wl4_dyn[k*8 + s] holds logical column jjL = s ^ ((k>>7)<<1).
    for (int idx = tid; idx < HH * 8; idx += 256) {
        int k = idx >> 3;
        int jjL = (idx & 7) ^ (((k >> 7) & 3) << 1);
        const float* r = rk + (size_t)k * G3 + i0 + jjL;
        wl4_dyn[idx] = make_float4(r[0], r[512], r[1024], 0.f);
    }
    const float* brec = gbias + G3;
    const float bz = brec[i], br_ = brec[512 + i], bh = brec[1024 + i];

    const float4* wp  = wl4_dyn + ks * 1024 + jjs;   // + kk*8 walks this thread's k-range

    for (int t = 0; t < TT; t++) {
        // ---- two-level wait: 8 threads each poll one group line (r8 verbatim) ----
        if (t > 0) {
            if (tid < NGRP) {
                const unsigned int tgt = (unsigned int)t * (NWG / NGRP);
                while (__hip_atomic_load(&grp[tid * 16], __ATOMIC_ACQUIRE,
                                         __HIP_MEMORY_SCOPE_AGENT) < tgt)
                    __builtin_amdgcn_s_sleep(1);
            }
        }
        __syncthreads();   // t=0: also covers weight staging

        // ---- stage h[t&1] -> LDS, swizzled: h4[idx] <- hgr[idx ^ ((idx>>10)&3)<<1] ----
        {
            const float4* hgr = (const float4*)(hg2 + (t & 1) * (HH * BB));
#pragma unroll
            for (int it = 0; it < 16; it++) {
                int idx = it * 256 + tid;
                h4[idx] = hgr[idx ^ ((((idx >> 10) & 3)) << 1)];
            }
        }
        __syncthreads();

        // mx loads (post-staging, r3 position)
        const float* mxr = mx + ((size_t)t * BB + batch) * G3;
        float mz = mxr[i], mr = mxr[512 + i], mh = mxr[1024 + i];

        // ---- inner: 128 k per thread, 2 b128 reads + 12 FMA per k ----
        float az0 = 0.f, az1 = 0.f, az2 = 0.f, az3 = 0.f;
        float ar0 = 0.f, ar1 = 0.f, ar2 = 0.f, ar3 = 0.f;
        float ah0 = 0.f, ah1 = 0.f, ah2 = 0.f, ah3 = 0.f;
        const float4* hp2 = &h4[ks * 1024 + bqs];
#pragma unroll 4
        for (int kk = 0; kk < 128; kk++) {
            float4 w = wp[kk * 8];     // {wz,wr,wc,_} col jj, k=ks*128+kk (8-way broadcast)
            float4 h = hp2[kk * 8];    // h[k][bq*4 .. bq*4+3]
            az0 += w.x * h.x; az1 += w.x * h.y; az2 += w.x * h.z; az3 += w.x * h.w;
            ar0 += w.y * h.x; ar1 += w.y * h.y; ar2 += w.y * h.z; ar3 += w.y * h.w;
            ah0 += w.z * h.x; ah1 += w.z * h.y; ah2 += w.z * h.z; ah3 += w.z * h.w;
        }

        // ---- in-wave butterfly over ks lanes (lane bits 0-1): full-k sums, all lanes ----
        az0 += __shfl_xor(az0, 1); az1 += __shfl_xor(az1, 1);
        az2 += __shfl_xor(az2, 1); az3 += __shfl_xor(az3, 1);
        ar0 += __shfl_xor(ar0, 1); ar1 += __shfl_xor(ar1, 1);
        ar2 += __shfl_xor(ar2, 1); ar3 += __shfl_xor(ar3, 1);
        ah0 += __shfl_xor(ah0, 1); ah1 += __shfl_xor(ah1, 1);
        ah2 += __shfl_xor(ah2, 1); ah3 += __shfl_xor(ah3, 1);
        az0 += __shfl_xor(az0, 2); az1 += __shfl_xor(az1, 2);
        az2 += __shfl_xor(az2, 2); az3 += __shfl_xor(az3, 2);
        ar0 += __shfl_xor(ar0, 2); ar1 += __shfl_xor(ar1, 2);
        ar2 += __shfl_xor(ar2, 2); ar3 += __shfl_xor(ar3, 2);
        ah0 += __shfl_xor(ah0, 2); ah1 += __shfl_xor(ah1, 2);
        ah2 += __shfl_xor(ah2, 2); ah3 += __shfl_xor(ah3, 2);

        // ---- this thread finishes (col i, batch = bq*4+ks): pick c = ks ----
        float azt = sel4_(az0, az1, az2, az3, ks);
        float art = sel4_(ar0, ar1, ar2, ar3, ks);
        float aht = sel4_(ah0, ah1, ah2, ah3, ks);

        float z = sigmoidf_(mz + azt + bz);
        float r = sigmoidf_(mr + art + br_);
        float c = tanhf(mh + r * (aht + bh));
        float hold = ((const float*)&h4[i * 8 + (bq ^ ((((i >> 7) & 3)) << 1))])[ks];
        float hn = z * hold + (1.f - z) * c;

        hg2[((t + 1) & 1) * (HH * BB) + i * BB + batch] = hn;   // coalesced across ks,bq
        hs[((size_t)t * BB + batch) * HH + i] = hn;

        __threadfence();       // agent-scope release of hg2 writes
        __syncthreads();       // all threads fenced before arrival
        if (tid == 0)
            __hip_atomic_fetch_add(&grp[(wg >> 3) * 16], 1u,
                                   __ATOMIC_RELEASE, __HIP_MEMORY_SCOPE_AGENT);
    }
}

// ---------------- K3: sx[b][u][n] = sum_t data[b][t][n] * w1[t][u] + w1b[u] ----------------
__global__ __launch_bounds__(256) void k_sx(const float* __restrict__ data,
                                            const float* __restrict__ w1,
                                            const float* __restrict__ w1b,
                                            float* __restrict__ sx) {
    int bx = blockIdx.x;
    int b = bx >> 4, ug = bx & 15;
    int n = threadIdx.x;
    float acc[8] = {0, 0, 0, 0, 0, 0, 0, 0};
    const float* dp = data + (size_t)b * TT * NF + n;
    for (int t = 0; t < TT; t++) {
        float x = dp[(size_t)t * NF];
#pragma unroll
        for (int uu = 0; uu < 8; uu++) acc[uu] += x * w1[t * TT + ug * 8 + uu];
    }
#pragma unroll
    for (int uu = 0; uu < 8; uu++) {
        int u = ug * 8 + uu;
        sx[((size_t)b * TT + u) * NF + n] = acc[uu] + w1b[u];
    }
}

// ---------------- K4: hp[r][u] = hs[r][:] @ w2 + w2b  (r = t*32+b) ----------------
__global__ __launch_bounds__(256) void k_hp(const float* __restrict__ hs,
                                            const float* __restrict__ w2,
                                            const float* __restrict__ w2b,
                                            float* __restrict__ hp) {
    __shared__ float hsl[8 * HH];   // 16KB
    int r0 = blockIdx.x * 8;
    int tid = threadIdx.x;
    for (int idx = tid; idx < 8 * HH; idx += 256)
        hsl[idx] = hs[(size_t)r0 * HH + idx];
    __syncthreads();
    int u = tid & 127, rh = tid >> 7;
    float acc[4] = {0, 0, 0, 0};
    for (int k = 0; k < HH; k++) {
        float w = w2[k * TT + u];
#pragma unroll
        for (int rr = 0; rr < 4; rr++) acc[rr] += hsl[(rh * 4 + rr) * HH + k] * w;
    }
    float wb = w2b[u];
#pragma unroll
    for (int rr = 0; rr < 4; rr++)
        hp[(size_t)(r0 + rh * 4 + rr) * TT + u] = acc[rr] + wb;
}

// ---------------- K5: fused score + softmax + output ----------------
__global__ __launch_bounds__(256) void k_attn(const float* __restrict__ data,
                                              const float* __restrict__ sx,
                                              const float* __restrict__ hp,
                                              const float* __restrict__ v_w,
                                              const float* __restrict__ v_b,
                                              float* __restrict__ out) {
    __shared__ float hv[TT];
    __shared__ float vv[TT];
    __shared__ float red[8];
    int r = blockIdx.x;
    int b = r & 31;
    int n = threadIdx.x;
    if (n < TT) {
        hv[n] = hp[(size_t)r * TT + n];
        vv[n] = v_w[n];
    }
    __syncthreads();
    float s = v_b[0];
    const float* sxp = sx + (size_t)b * TT * NF + n;
    for (int u = 0; u < TT; u++) {
        float e = tanh_fast(sxp[(size_t)u * NF] + hv[u]);
        s += vv[u] * e;
    }
    float m = s;
#pragma unroll
    for (int off = 32; off >= 1; off >>= 1) m = fmaxf(m, __shfl_xor(m, off));
    int lane = n & 63, wid = n >> 6;
    if (lane == 0) red[wid] = m;
    __syncthreads();
    float bm = fmaxf(fmaxf(red[0], red[1]), fmaxf(red[2], red[3]));
    float p = __expf(s - bm);
    float ps = p;
#pragma unroll
    for (int off = 32; off >= 1; off >>= 1) ps += __shfl_xor(ps, off);
    if (lane == 0) red[4 + wid] = ps;
    __syncthreads();
    float denom = red[4] + red[5] + red[6] + red[7];
    float alpha = p / denom;
    size_t idx = (size_t)r * NF + n;
    out[idx] = data[idx] * alpha;
}

extern "C" void kernel_launch(void* const* d_in, const int* in_sizes, int n_in,
                              void* d_out, int out_size, void* d_ws, size_t ws_size,
                              hipStream_t stream) {
    const float* data = (const float*)d_in[0];
    const float* h0   = (const float*)d_in[1];
    const float* gk   = (const float*)d_in[2];
    const float* rk   = (const float*)d_in[3];
    const float* gb   = (const float*)d_in[4];
    const float* w1   = (const float*)d_in[5];
    const float* w1b  = (const float*)d_in[6];
    const float* w2   = (const float*)d_in[7];
    const float* w2b  = (const float*)d_in[8];
    const float* vw   = (const float*)d_in[9];
    const float* vb   = (const float*)d_in[10];
    float* out = (float*)d_out;

    float* ws  = (float*)d_ws;
    float* mx  = ws;                    // 128*32*1536 = 6291456
    float* hs  = mx + 6291456;          // 128*32*512  = 2097152
    float* sxb = hs + 2097152;          // 32*128*256  = 1048576
    float* hp  = sxb + 1048576;         // 128*32*128  = 524288
    float* hg2 = hp + 524288;           // 2*512*32    = 32768
    unsigned int* grp = (unsigned int*)(hg2 + 32768);   // 8 lines x 16 dwords

    k_hinit<<<64, 256, 0, stream>>>(h0, hg2, grp);
    k_mx<<<512, 256, 0, stream>>>(data, gk, gb, mx);

    void* args[] = {(void*)&rk, (void*)&gb, (void*)&mx,
                    (void*)&hg2, (void*)&hs, (void*)&grp};
    hipLaunchCooperativeKernel((const void*)k_gru9, dim3(NWG), dim3(256), args,
                               65536, stream);

    k_sx<<<512, 256, 0, stream>>>(data, w1, w1b, sxb);
    k_hp<<<512, 256, 0, stream>>>(hs, w2, w2b, hp);
    k_attn<<<4096, 256, 0, stream>>>(data, sxb, hp, vw, vb, out);
}

// Round 10
// 1263.451 us; speedup vs baseline: 6.5164x; 1.7508x over previous
//
#include <hip/hip_runtime.h>
#include <math.h>

#define BB 32     // batch
#define TT 128    // time steps
#define NF 256    // input features
#define HH 512    // hidden
#define G3 1536   // 3*H
#define NWG 64    // GRU workgroups (column partition)

__device__ __forceinline__ float sigmoidf_(float x) { return 1.f / (1.f + __expf(-x)); }
__device__ __forceinline__ float tanh_fast(float x) {
    float e = __expf(2.f * x);
    return 1.f - 2.f / (e + 1.f);
}
__device__ __forceinline__ float sel4_(float a0, float a1, float a2, float a3, int s) {
    float s01 = (s & 1) ? a1 : a0;
    float s23 = (s & 1) ? a3 : a2;
    return (s & 2) ? s23 : s01;
}

// ---------------- K0a: init h double buffer (transpose h0 -> [i][b]) ----------------
__global__ __launch_bounds__(256) void k_hinit(const float* __restrict__ h0,
                                               float* __restrict__ hg2) {
    int idx = blockIdx.x * 256 + threadIdx.x;   // 64 blocks -> 16384
    int i = idx & 511, b = idx >> 9;
    hg2[i * BB + b] = h0[b * HH + i];
}

// ---------------- K0b: pack rk into per-WG swizzled float4 blocks ----------------
// rk4[wg*4096 + k*8 + s] = {rk[k][col], rk[k][512+col], rk[k][1024+col], 0},
// col = wg*8 + (s ^ (((k>>7)&3)<<1))   — exactly r9's wl4_dyn layout.
__global__ __launch_bounds__(256) void k_pack(const float* __restrict__ rk,
                                              float4* __restrict__ rk4) {
    int gidx = blockIdx.x * 256 + threadIdx.x;   // 1024 blocks -> 262144
    int wg = gidx >> 12;
    int idx = gidx & 4095;
    int k = idx >> 3, s = idx & 7;
    int jjL = s ^ (((k >> 7) & 3) << 1);
    const float* r = rk + (size_t)k * G3 + wg * 8 + jjL;
    rk4[gidx] = make_float4(r[0], r[512], r[1024], 0.f);
}

// ---------------- K1: mx[t][b][j] = data[b][t][:] @ gru_kernel + b_in ----------------
__global__ __launch_bounds__(256) void k_mx(const float* __restrict__ data,
                                            const float* __restrict__ gk,
                                            const float* __restrict__ bias_in,
                                            float* __restrict__ mx) {
    __shared__ __align__(16) float xs[NF * 8];   // [k][bb]
    int bx = blockIdx.x;
    int t = bx >> 2, b0 = (bx & 3) * 8;
    int tid = threadIdx.x;
    for (int idx = tid; idx < 8 * NF; idx += 256) {
        int bb = idx >> 8, k = idx & 255;
        xs[k * 8 + bb] = data[((size_t)(b0 + bb) * TT + t) * NF + k];
    }
    __syncthreads();
    float acc[6][8];
#pragma unroll
    for (int jj = 0; jj < 6; jj++)
#pragma unroll
        for (int bb = 0; bb < 8; bb++) acc[jj][bb] = 0.f;

    for (int k = 0; k < NF; k++) {
        float4 xa = *(const float4*)&xs[k * 8];
        float4 xb = *(const float4*)&xs[k * 8 + 4];
        float xv[8] = {xa.x, xa.y, xa.z, xa.w, xb.x, xb.y, xb.z, xb.w};
#pragma unroll
        for (int jj = 0; jj < 6; jj++) {
            float g = gk[(size_t)k * G3 + jj * 256 + tid];
#pragma unroll
            for (int bb = 0; bb < 8; bb++) acc[jj][bb] += g * xv[bb];
        }
    }
#pragma unroll
    for (int jj = 0; jj < 6; jj++) {
        int j = jj * 256 + tid;
        float bi = bias_in[j];
#pragma unroll
        for (int bb = 0; bb < 8; bb++)
            mx[((size_t)t * BB + b0 + bb) * G3 + j] = acc[jj][bb] + bi;
    }
}

// ---------------- K2: ONE GRU STEP per launch — r9 compute verbatim, no in-kernel sync ----------------
// 64 WGs x 256 threads, regular launch. Inter-step ordering/visibility = stream dispatch
// boundaries (hardware release/acquire, cross-XCD safe). Thread = (jj = tid>>5: col,
// bq = (tid>>2)&7: batch quad, ks = tid&3: k-split). Weights staged as a contiguous
// 64KB copy from prepacked rk4 (L2-hot). Inner: 2 b128 LDS reads + 12 FMA per k.
extern __shared__ float4 wl4_dyn[];   // 4096 float4 = 64 KB, r9 swizzled layout

__global__ __launch_bounds__(256, 1) void k_gstep(const float4* __restrict__ rk4,
                                                  const float* __restrict__ gbias,
                                                  const float* __restrict__ mx,
                                                  float* __restrict__ hg2,
                                                  float* __restrict__ hs,
                                                  int t) {
    __shared__ __align__(16) float4 h4[HH * 8];   // 64 KB: h[k][batch-quad], swizzled
    const int tid = threadIdx.x;
    const int wg  = blockIdx.x;
    const int jj  = tid >> 5;          // 0..7 column within slice
    const int bq  = (tid >> 2) & 7;    // 0..7 batch quad
    const int ks  = tid & 3;           // 0..3 k-split (128 k each)
    const int i0  = wg * 8;
    const int i   = i0 + jj;
    const int batch = bq * 4 + ks;
    const int jjs = jj ^ (ks << 1);    // swizzled weight slot for this thread's k-range
    const int bqs = bq ^ (ks << 1);    // swizzled h slot for this thread's k-range

    // ---- stage weight slice: contiguous 64 KB copy (prepacked, swizzle baked in) ----
    {
        const float4* src = rk4 + (size_t)wg * 4096;
#pragma unroll
        for (int it = 0; it < 16; it++) {
            int idx = it * 256 + tid;
            wl4_dyn[idx] = src[idx];
        }
    }
    // ---- stage h[t&1] -> LDS, swizzled (r9 verbatim) ----
    {
        const float4* hgr = (const float4*)(hg2 + (t & 1) * (HH * BB));
#pragma unroll
        for (int it = 0; it < 16; it++) {
            int idx = it * 256 + tid;
            h4[idx] = hgr[idx ^ ((((idx >> 10) & 3)) << 1)];
        }
    }
    const float* brec = gbias + G3;
    const float bz = brec[i], br_ = brec[512 + i], bh = brec[1024 + i];
    __syncthreads();

    // mx loads (post-staging, r9 position)
    const float* mxr = mx + ((size_t)t * BB + batch) * G3;
    float mz = mxr[i], mr = mxr[512 + i], mh = mxr[1024 + i];

    // ---- inner: 128 k per thread, 2 b128 reads + 12 FMA per k (r9 verbatim) ----
    float az0 = 0.f, az1 = 0.f, az2 = 0.f, az3 = 0.f;
    float ar0 = 0.f, ar1 = 0.f, ar2 = 0.f, ar3 = 0.f;
    float ah0 = 0.f, ah1 = 0.f, ah2 = 0.f, ah3 = 0.f;
    const float4* wp  = wl4_dyn + ks * 1024 + jjs;
    const float4* hp2 = &h4[ks * 1024 + bqs];
#pragma unroll 4
    for (int kk = 0; kk < 128; kk++) {
        float4 w = wp[kk * 8];     // {wz,wr,wc,_} col jj, k=ks*128+kk (8-way broadcast)
        float4 h = hp2[kk * 8];    // h[k][bq*4 .. bq*4+3]
        az0 += w.x * h.x; az1 += w.x * h.y; az2 += w.x * h.z; az3 += w.x * h.w;
        ar0 += w.y * h.x; ar1 += w.y * h.y; ar2 += w.y * h.z; ar3 += w.y * h.w;
        ah0 += w.z * h.x; ah1 += w.z * h.y; ah2 += w.z * h.z; ah3 += w.z * h.w;
    }

    // ---- in-wave butterfly over ks lanes (r9 verbatim) ----
    az0 += __shfl_xor(az0, 1); az1 += __shfl_xor(az1, 1);
    az2 += __shfl_xor(az2, 1); az3 += __shfl_xor(az3, 1);
    ar0 += __shfl_xor(ar0, 1); ar1 += __shfl_xor(ar1, 1);
    ar2 += __shfl_xor(ar2, 1); ar3 += __shfl_xor(ar3, 1);
    ah0 += __shfl_xor(ah0, 1); ah1 += __shfl_xor(ah1, 1);
    ah2 += __shfl_xor(ah2, 1); ah3 += __shfl_xor(ah3, 1);
    az0 += __shfl_xor(az0, 2); az1 += __shfl_xor(az1, 2);
    az2 += __shfl_xor(az2, 2); az3 += __shfl_xor(az3, 2);
    ar0 += __shfl_xor(ar0, 2); ar1 += __shfl_xor(ar1, 2);
    ar2 += __shfl_xor(ar2, 2); ar3 += __shfl_xor(ar3, 2);
    ah0 += __shfl_xor(ah0, 2); ah1 += __shfl_xor(ah1, 2);
    ah2 += __shfl_xor(ah2, 2); ah3 += __shfl_xor(ah3, 2);

    float azt = sel4_(az0, az1, az2, az3, ks);
    float art = sel4_(ar0, ar1, ar2, ar3, ks);
    float aht = sel4_(ah0, ah1, ah2, ah3, ks);

    float z = sigmoidf_(mz + azt + bz);
    float r = sigmoidf_(mr + art + br_);
    float c = tanhf(mh + r * (aht + bh));
    float hold = ((const float*)&h4[i * 8 + (bq ^ ((((i >> 7) & 3)) << 1))])[ks];
    float hn = z * hold + (1.f - z) * c;

    hg2[((t + 1) & 1) * (HH * BB) + i * BB + batch] = hn;   // coalesced across ks,bq
    hs[((size_t)t * BB + batch) * HH + i] = hn;
}

// ---------------- K3: sx[b][u][n] = sum_t data[b][t][n] * w1[t][u] + w1b[u] ----------------
__global__ __launch_bounds__(256) void k_sx(const float* __restrict__ data,
                                            const float* __restrict__ w1,
                                            const float* __restrict__ w1b,
                                            float* __restrict__ sx) {
    int bx = blockIdx.x;
    int b = bx >> 4, ug = bx & 15;
    int n = threadIdx.x;
    float acc[8] = {0, 0, 0, 0, 0, 0, 0, 0};
    const float* dp = data + (size_t)b * TT * NF + n;
    for (int t = 0; t < TT; t++) {
        float x = dp[(size_t)t * NF];
#pragma unroll
        for (int uu = 0; uu < 8; uu++) acc[uu] += x * w1[t * TT + ug * 8 + uu];
    }
#pragma unroll
    for (int uu = 0; uu < 8; uu++) {
        int u = ug * 8 + uu;
        sx[((size_t)b * TT + u) * NF + n] = acc[uu] + w1b[u];
    }
}

// ---------------- K4: hp[r][u] = hs[r][:] @ w2 + w2b  (r = t*32+b) ----------------
__global__ __launch_bounds__(256) void k_hp(const float* __restrict__ hs,
                                            const float* __restrict__ w2,
                                            const float* __restrict__ w2b,
                                            float* __restrict__ hp) {
    __shared__ float hsl[8 * HH];   // 16KB
    int r0 = blockIdx.x * 8;
    int tid = threadIdx.x;
    for (int idx = tid; idx < 8 * HH; idx += 256)
        hsl[idx] = hs[(size_t)r0 * HH + idx];
    __syncthreads();
    int u = tid & 127, rh = tid >> 7;
    float acc[4] = {0, 0, 0, 0};
    for (int k = 0; k < HH; k++) {
        float w = w2[k * TT + u];
#pragma unroll
        for (int rr = 0; rr < 4; rr++) acc[rr] += hsl[(rh * 4 + rr) * HH + k] * w;
    }
    float wb = w2b[u];
#pragma unroll
    for (int rr = 0; rr < 4; rr++)
        hp[(size_t)(r0 + rh * 4 + rr) * TT + u] = acc[rr] + wb;
}

// ---------------- K5: fused score + softmax + output ----------------
__global__ __launch_bounds__(256) void k_attn(const float* __restrict__ data,
                                              const float* __restrict__ sx,
                                              const float* __restrict__ hp,
                                              const float* __restrict__ v_w,
                                              const float* __restrict__ v_b,
                                              float* __restrict__ out) {
    __shared__ float hv[TT];
    __shared__ float vv[TT];
    __shared__ float red[8];
    int r = blockIdx.x;
    int b = r & 31;
    int n = threadIdx.x;
    if (n < TT) {
        hv[n] = hp[(size_t)r * TT + n];
        vv[n] = v_w[n];
    }
    __syncthreads();
    float s = v_b[0];
    const float* sxp = sx + (size_t)b * TT * NF + n;
    for (int u = 0; u < TT; u++) {
        float e = tanh_fast(sxp[(size_t)u * NF] + hv[u]);
        s += vv[u] * e;
    }
    float m = s;
#pragma unroll
    for (int off = 32; off >= 1; off >>= 1) m = fmaxf(m, __shfl_xor(m, off));
    int lane = n & 63, wid = n >> 6;
    if (lane == 0) red[wid] = m;
    __syncthreads();
    float bm = fmaxf(fmaxf(red[0], red[1]), fmaxf(red[2], red[3]));
    float p = __expf(s - bm);
    float ps = p;
#pragma unroll
    for (int off = 32; off >= 1; off >>= 1) ps += __shfl_xor(ps, off);
    if (lane == 0) red[4 + wid] = ps;
    __syncthreads();
    float denom = red[4] + red[5] + red[6] + red[7];
    float alpha = p / denom;
    size_t idx = (size_t)r * NF + n;
    out[idx] = data[idx] * alpha;
}

extern "C" void kernel_launch(void* const* d_in, const int* in_sizes, int n_in,
                              void* d_out, int out_size, void* d_ws, size_t ws_size,
                              hipStream_t stream) {
    const float* data = (const float*)d_in[0];
    const float* h0   = (const float*)d_in[1];
    const float* gk   = (const float*)d_in[2];
    const float* rk   = (const float*)d_in[3];
    const float* gb   = (const float*)d_in[4];
    const float* w1   = (const float*)d_in[5];
    const float* w1b  = (const float*)d_in[6];
    const float* w2   = (const float*)d_in[7];
    const float* w2b  = (const float*)d_in[8];
    const float* vw   = (const float*)d_in[9];
    const float* vb   = (const float*)d_in[10];
    float* out = (float*)d_out;

    float* ws  = (float*)d_ws;
    float* mx  = ws;                    // 128*32*1536 = 6291456
    float* hs  = mx + 6291456;          // 128*32*512  = 2097152
    float* sxb = hs + 2097152;          // 32*128*256  = 1048576
    float* hp  = sxb + 1048576;         // 128*32*128  = 524288
    float* hg2 = hp + 524288;           // 2*512*32    = 32768
    float4* rk4 = (float4*)(hg2 + 32768);   // 262144 float4 = 4 MB

    k_hinit<<<64, 256, 0, stream>>>(h0, hg2);
    k_pack<<<1024, 256, 0, stream>>>(rk, rk4);
    k_mx<<<512, 256, 0, stream>>>(data, gk, gb, mx);

    for (int t = 0; t < TT; t++)
        k_gstep<<<NWG, 256, 65536, stream>>>(rk4, gb, mx, hg2, hs, t);

    k_sx<<<512, 256, 0, stream>>>(data, w1, w1b, sxb);
    k_hp<<<512, 256, 0, stream>>>(hs, w2, w2b, hp);
    k_attn<<<4096, 256, 0, stream>>>(data, sxb, hp, vw, vb, out);
}